// Round 1
// baseline (4910.656 us; speedup 1.0000x reference)
//
#include <hip/hip_runtime.h>
#include <cstdint>
#include <cstddef>

#define Nn 50000
#define Ee 500000
#define ETOT (Ee + Nn)
#define Tt 8
#define FIN 128
#define Dd 256
#define Hh 32
#define Cc 8
#define OUTC 64
#define EPSC 1e-5f

// ---------------- precompute: folded weight matrices ----------------
// BmatT[j,k] = sum_r Wq[r,k]*Wk[r,j];  bqk[j] = sum_r bq[r]*Wk[r,j]
__global__ void k_bmat(const float* __restrict__ Wqkv, const float* __restrict__ bqkv,
                       float* __restrict__ BmatT, float* __restrict__ bqk)
{
    int gid = blockIdx.x * 256 + threadIdx.x;
    if (gid < Dd * Dd) {
        int j = gid >> 8, k = gid & 255;
        float s = 0.f;
        for (int r = 0; r < Dd; ++r)
            s += Wqkv[r * Dd + k] * Wqkv[(Dd + r) * Dd + j];
        BmatT[j * Dd + k] = s;
    } else if (gid < Dd * Dd + Dd) {
        int j = gid - Dd * Dd;
        float s = 0.f;
        for (int r = 0; r < Dd; ++r)
            s += bqkv[r] * Wqkv[(Dd + r) * Dd + j];
        bqk[j] = s;
    }
}

// WoWv[i,j] = sum_r Wo[i,r]*Wv[r,j];  tmp[i] = sum_r Wo[i,r]*bv[r] + bo[i]
__global__ void k_wowv(const float* __restrict__ Wo, const float* __restrict__ Wqkv,
                       const float* __restrict__ bqkv, const float* __restrict__ bo,
                       float* __restrict__ WoWv, float* __restrict__ tmpv)
{
    int gid = blockIdx.x * 256 + threadIdx.x;
    if (gid < Dd * Dd) {
        int i = gid >> 8, j = gid & 255;
        float s = 0.f;
        for (int r = 0; r < Dd; ++r)
            s += Wo[i * Dd + r] * Wqkv[(2 * Dd + r) * Dd + j];
        WoWv[i * Dd + j] = s;
    } else if (gid < Dd * Dd + Dd) {
        int i = gid - Dd * Dd;
        float s = 0.f;
        for (int r = 0; r < Dd; ++r)
            s += Wo[i * Dd + r] * bqkv[2 * Dd + r];
        tmpv[i] = s + bo[i];
    }
}

// Mc[o,j] = sum_i Wout[o,i]*WoWv[i,j];  cvec[o] = sum_i Wout[o,i]*tmp[i] + bout[o]
__global__ void k_mcomb(const float* __restrict__ Wout, const float* __restrict__ WoWv,
                        const float* __restrict__ tmpv, const float* __restrict__ bout,
                        float* __restrict__ Mc, float* __restrict__ cvec)
{
    int gid = blockIdx.x * 256 + threadIdx.x;
    if (gid < OUTC * Dd) {
        int o = gid >> 8, j = gid & 255;
        float s = 0.f;
        for (int i = 0; i < Dd; ++i)
            s += Wout[o * Dd + i] * WoWv[i * Dd + j];
        Mc[o * Dd + j] = s;
    } else if (gid < OUTC * Dd + OUTC) {
        int o = gid - OUTC * Dd;
        float s = 0.f;
        for (int i = 0; i < Dd; ++i)
            s += Wout[o * Dd + i] * tmpv[i];
        cvec[o] = s + bout[o];
    }
}

// ---------------- CSR build ----------------
__global__ void k_deg(const int* __restrict__ dstp, int* __restrict__ deg)
{
    int e = blockIdx.x * 256 + threadIdx.x;
    if (e >= ETOT) return;
    int d = (e < Ee) ? dstp[e] : (e - Ee);
    atomicAdd(&deg[d], 1);
}

__global__ void k_scan(const int* __restrict__ deg, int* __restrict__ rowp, int* __restrict__ wp)
{
    __shared__ int sums[256];
    const int t = threadIdx.x;
    const int chunk = (Nn + 255) / 256;
    int lo = t * chunk;
    int hi = lo + chunk;
    if (lo > Nn) lo = Nn;
    if (hi > Nn) hi = Nn;
    int s = 0;
    for (int i = lo; i < hi; ++i) s += deg[i];
    sums[t] = s;
    __syncthreads();
    for (int off = 1; off < 256; off <<= 1) {
        int v = (t >= off) ? sums[t - off] : 0;
        __syncthreads();
        sums[t] += v;
        __syncthreads();
    }
    int run = (t == 0) ? 0 : sums[t - 1];
    for (int i = lo; i < hi; ++i) {
        rowp[i] = run;
        wp[i] = run;
        run += deg[i];
    }
    if (t == 255) rowp[Nn] = run;
}

__global__ void k_fill(const int* __restrict__ srcp, const int* __restrict__ dstp,
                       int* __restrict__ wp, int* __restrict__ elist)
{
    int e = blockIdx.x * 256 + threadIdx.x;
    if (e >= ETOT) return;
    int s, d;
    if (e < Ee) { s = srcp[e]; d = dstp[e]; }
    else        { s = e - Ee;  d = s; }
    int pos = atomicAdd(&wp[d], 1);
    elist[pos] = s;
}

// ---------------- fp32 NT GEMM: C[M,N] = A[M,K] @ B[N,K]^T (+bias) ----------------
template<int BM, int BN, int BK, int TM, int TN>
__global__ __launch_bounds__((BM / TM) * (BN / TN)) void k_gemm_nt(
    const float* __restrict__ A, const float* __restrict__ B, const float* __restrict__ bias,
    float* __restrict__ C, int M, int Ncols, int K)
{
    static_assert(TM == 8 && TN == 8 && BK == 16, "fixed microkernel");
    constexpr int NTHR = (BM / TM) * (BN / TN);
    __shared__ float As[BK][BM];
    __shared__ float Bs[BK][BN];
    const int tx = threadIdx.x, ty = threadIdx.y;
    const int tid = ty * (BN / TN) + tx;
    const int m0 = blockIdx.y * BM, n0 = blockIdx.x * BN;
    float acc[TM][TN] = {};
    for (int k0 = 0; k0 < K; k0 += BK) {
        constexpr int AITER = (BM * BK / 4) / NTHR;
        #pragma unroll
        for (int it = 0; it < AITER; ++it) {
            int f = tid + it * NTHR;
            int r = f >> 2;
            int k4 = (f & 3) * 4;
            float4 v = make_float4(0.f, 0.f, 0.f, 0.f);
            int gm = m0 + r;
            if (gm < M) v = *(const float4*)(A + (size_t)gm * K + k0 + k4);
            As[k4 + 0][r] = v.x; As[k4 + 1][r] = v.y; As[k4 + 2][r] = v.z; As[k4 + 3][r] = v.w;
        }
        constexpr int BITER = (BN * BK / 4) / NTHR;
        #pragma unroll
        for (int it = 0; it < BITER; ++it) {
            int f = tid + it * NTHR;
            int r = f >> 2;
            int k4 = (f & 3) * 4;
            float4 v = *(const float4*)(B + (size_t)(n0 + r) * K + k0 + k4);
            Bs[k4 + 0][r] = v.x; Bs[k4 + 1][r] = v.y; Bs[k4 + 2][r] = v.z; Bs[k4 + 3][r] = v.w;
        }
        __syncthreads();
        #pragma unroll
        for (int kk = 0; kk < BK; ++kk) {
            float4 a0 = *(const float4*)&As[kk][ty * TM];
            float4 a1 = *(const float4*)&As[kk][ty * TM + 4];
            float4 b0 = *(const float4*)&Bs[kk][tx * TN];
            float4 b1 = *(const float4*)&Bs[kk][tx * TN + 4];
            float av[8] = {a0.x, a0.y, a0.z, a0.w, a1.x, a1.y, a1.z, a1.w};
            float bv[8] = {b0.x, b0.y, b0.z, b0.w, b1.x, b1.y, b1.z, b1.w};
            #pragma unroll
            for (int i = 0; i < TM; ++i)
                #pragma unroll
                for (int j = 0; j < TN; ++j)
                    acc[i][j] += av[i] * bv[j];
        }
        __syncthreads();
    }
    float bb[TN];
    #pragma unroll
    for (int j = 0; j < TN; ++j) bb[j] = bias ? bias[n0 + tx * TN + j] : 0.f;
    #pragma unroll
    for (int i = 0; i < TM; ++i) {
        int m = m0 + ty * TM + i;
        if (m >= M) continue;
        float* crow = C + (size_t)m * Ncols + n0 + tx * TN;
        float4 v0 = make_float4(acc[i][0] + bb[0], acc[i][1] + bb[1], acc[i][2] + bb[2], acc[i][3] + bb[3]);
        float4 v1 = make_float4(acc[i][4] + bb[4], acc[i][5] + bb[5], acc[i][6] + bb[6], acc[i][7] + bb[7]);
        *(float4*)crow = v0;
        *(float4*)(crow + 4) = v1;
    }
}

// ---------------- attention logits per node: es/ed ----------------
__global__ void k_esed(const float* __restrict__ h, const float* __restrict__ a_s,
                       const float* __restrict__ a_d, float* __restrict__ es, float* __restrict__ ed)
{
    int gid = blockIdx.x * 256 + threadIdx.x;
    if (gid >= Nn * Hh) return;
    int hh = gid & (Hh - 1);
    const float* hp = h + (size_t)(gid >> 5) * Dd + hh * Cc;
    float4 h0 = *(const float4*)hp;
    float4 h1 = *(const float4*)(hp + 4);
    float4 s0 = *(const float4*)(a_s + hh * Cc);
    float4 s1 = *(const float4*)(a_s + hh * Cc + 4);
    float4 d0 = *(const float4*)(a_d + hh * Cc);
    float4 d1 = *(const float4*)(a_d + hh * Cc + 4);
    es[gid] = h0.x * s0.x + h0.y * s0.y + h0.z * s0.z + h0.w * s0.w
            + h1.x * s1.x + h1.y * s1.y + h1.z * s1.z + h1.w * s1.w;
    ed[gid] = h0.x * d0.x + h0.y * d0.y + h0.z * d0.z + h0.w * d0.w
            + h1.x * d1.x + h1.y * d1.y + h1.z * d1.z + h1.w * d1.w;
}

// ---------------- GAT aggregation: one wave per dst node, online softmax ----------------
template<bool DO_LN>
__global__ __launch_bounds__(256) void k_agg(
    const float* __restrict__ h, const float* __restrict__ es, const float* __restrict__ ed,
    const int* __restrict__ rowp, const int* __restrict__ elist,
    const float* __restrict__ bvec, const float* __restrict__ lng, const float* __restrict__ lnb,
    float* __restrict__ outp)
{
    int lane = threadIdx.x & 63;
    int n = blockIdx.x * 4 + (threadIdx.x >> 6);
    if (n >= Nn) return;
    int hh = lane >> 1;          // head (8 channels = 2 lanes per head)
    int ch = lane * 4;           // 4 consecutive channels per lane
    float edv = ed[n * Hh + hh];
    int r0 = rowp[n], r1 = rowp[n + 1];
    float mX = -3.0e38f, den = 0.f;
    float ax = 0.f, ay = 0.f, az = 0.f, aw = 0.f;
    for (int i = r0; i < r1; ++i) {
        int s = elist[i];
        float x = es[s * Hh + hh] + edv;
        x = (x > 0.f) ? x : 0.2f * x;          // LeakyReLU(0.2)
        float mN = fmaxf(mX, x);
        float scl = __expf(mX - mN);
        float p = __expf(x - mN);
        den = den * scl + p;
        const float4 hv = *(const float4*)(h + (size_t)s * Dd + ch);
        ax = ax * scl + p * hv.x;
        ay = ay * scl + p * hv.y;
        az = az * scl + p * hv.z;
        aw = aw * scl + p * hv.w;
        mX = mN;
    }
    float inv = 1.0f / den;
    float ox = ax * inv + bvec[ch];
    float oy = ay * inv + bvec[ch + 1];
    float oz = az * inv + bvec[ch + 2];
    float ow = aw * inv + bvec[ch + 3];
    if (DO_LN) {
        float s1 = ox + oy + oz + ow;
        float s2 = ox * ox + oy * oy + oz * oz + ow * ow;
        #pragma unroll
        for (int off = 32; off > 0; off >>= 1) {
            s1 += __shfl_xor(s1, off);
            s2 += __shfl_xor(s2, off);
        }
        float mu = s1 * (1.0f / Dd);
        float var = s2 * (1.0f / Dd) - mu * mu;
        float rstd = rsqrtf(var + EPSC);
        ox = fmaxf((ox - mu) * rstd * lng[ch]     + lnb[ch],     0.f);
        oy = fmaxf((oy - mu) * rstd * lng[ch + 1] + lnb[ch + 1], 0.f);
        oz = fmaxf((oz - mu) * rstd * lng[ch + 2] + lnb[ch + 2], 0.f);
        ow = fmaxf((ow - mu) * rstd * lng[ch + 3] + lnb[ch + 3], 0.f);
    }
    *(float4*)(outp + (size_t)n * Dd + ch) = make_float4(ox, oy, oz, ow);
}

// ---------------- temporal attention (last step only): z = sum_s w_s emb[s,n,:] ----------------
__global__ __launch_bounds__(256) void k_attn(const float* __restrict__ emb,
                                              const float* __restrict__ qt,
                                              float* __restrict__ z)
{
    int lane = threadIdx.x & 63;
    int n = blockIdx.x * 4 + (threadIdx.x >> 6);
    if (n >= Nn) return;
    float4 q = *(const float4*)(qt + (size_t)n * Dd + lane * 4);
    float4 e[Tt];
    float sc[Tt];
    #pragma unroll
    for (int s = 0; s < Tt; ++s) {
        e[s] = *(const float4*)(emb + ((size_t)s * Nn + n) * Dd + lane * 4);
        sc[s] = q.x * e[s].x + q.y * e[s].y + q.z * e[s].z + q.w * e[s].w;
    }
    #pragma unroll
    for (int off = 32; off > 0; off >>= 1)
        #pragma unroll
        for (int s = 0; s < Tt; ++s) sc[s] += __shfl_xor(sc[s], off);
    float mx = -3.0e38f;
    #pragma unroll
    for (int s = 0; s < Tt; ++s) { sc[s] *= 0.0625f; mx = fmaxf(mx, sc[s]); }  // /sqrt(256)
    float w[Tt], den = 0.f;
    #pragma unroll
    for (int s = 0; s < Tt; ++s) { w[s] = __expf(sc[s] - mx); den += w[s]; }
    float inv = 1.0f / den;
    float zx = 0.f, zy = 0.f, zz = 0.f, zw = 0.f;
    #pragma unroll
    for (int s = 0; s < Tt; ++s) {
        float ws = w[s] * inv;
        zx += ws * e[s].x; zy += ws * e[s].y; zz += ws * e[s].z; zw += ws * e[s].w;
    }
    *(float4*)(z + (size_t)n * Dd + lane * 4) = make_float4(zx, zy, zz, zw);
}

// ---------------- BatchNorm stats over N ----------------
__global__ __launch_bounds__(256) void k_bnstat(const float* __restrict__ logits,
                                                float* __restrict__ bsum, float* __restrict__ bsq)
{
    __shared__ float ls[256], lq[256];
    int t = threadIdx.x;
    int ch = t & 63;
    float s = 0.f, q = 0.f;
    for (int row = blockIdx.x * 4 + (t >> 6); row < Nn; row += gridDim.x * 4) {
        float v = logits[(size_t)row * OUTC + ch];
        s += v; q += v * v;
    }
    ls[t] = s; lq[t] = q;
    __syncthreads();
    if (t < 64) {
        s = ls[t] + ls[t + 64] + ls[t + 128] + ls[t + 192];
        q = lq[t] + lq[t + 64] + lq[t + 128] + lq[t + 192];
        atomicAdd(&bsum[t], s);
        atomicAdd(&bsq[t], q);
    }
}

// ---------------- BN apply + log_softmax ----------------
__global__ __launch_bounds__(256) void k_final(const float* __restrict__ logits,
                                               const float* __restrict__ bsum, const float* __restrict__ bsq,
                                               const float* __restrict__ g, const float* __restrict__ b,
                                               float* __restrict__ outp)
{
    int lane = threadIdx.x & 63;
    int row = blockIdx.x * 4 + (threadIdx.x >> 6);
    if (row >= Nn) return;
    float v = logits[(size_t)row * OUTC + lane];
    float mu = bsum[lane] * (1.0f / Nn);
    float var = bsq[lane] * (1.0f / Nn) - mu * mu;
    float y = (v - mu) * rsqrtf(var + EPSC) * g[lane] + b[lane];
    float mx = y;
    #pragma unroll
    for (int off = 32; off > 0; off >>= 1) mx = fmaxf(mx, __shfl_xor(mx, off));
    float ex = __expf(y - mx);
    float den = ex;
    #pragma unroll
    for (int off = 32; off > 0; off >>= 1) den += __shfl_xor(den, off);
    outp[(size_t)row * OUTC + lane] = y - mx - __logf(den);
}

// ---------------- launch ----------------
extern "C" void kernel_launch(void* const* d_in, const int* in_sizes, int n_in,
                              void* d_out, int out_size, void* d_ws, size_t ws_size,
                              hipStream_t stream)
{
    const float* feats = (const float*)d_in[0];
    const int*   eidx  = (const int*)d_in[1];
    const float* W1    = (const float*)d_in[2];
    const float* a_s1  = (const float*)d_in[3];
    const float* a_d1  = (const float*)d_in[4];
    const float* b1    = (const float*)d_in[5];
    const float* W2    = (const float*)d_in[6];
    const float* a_s2  = (const float*)d_in[7];
    const float* a_d2  = (const float*)d_in[8];
    const float* b2    = (const float*)d_in[9];
    const float* ln_g  = (const float*)d_in[10];
    const float* ln_b  = (const float*)d_in[11];
    const float* Wqkv  = (const float*)d_in[12];
    const float* bqkv  = (const float*)d_in[13];
    const float* Wo    = (const float*)d_in[14];
    const float* bo    = (const float*)d_in[15];
    const float* Wout  = (const float*)d_in[16];
    const float* bout  = (const float*)d_in[17];
    const float* bn_g  = (const float*)d_in[18];
    const float* bn_b  = (const float*)d_in[19];
    float* outp = (float*)d_out;

    char* p = (char*)d_ws;
    auto alloc = [&](size_t bytes) -> void* {
        void* r = (void*)p;
        p += (bytes + 255) & ~(size_t)255;
        return r;
    };
    float* emb    = (float*)alloc((size_t)Tt * Nn * Dd * 4);   // 409.6 MB
    float* bufH   = (float*)alloc((size_t)Nn * Dd * 4);        // 51.2 MB
    float* bufX   = (float*)alloc((size_t)Nn * Dd * 4);        // 51.2 MB
    float* es     = (float*)alloc((size_t)Nn * Hh * 4);
    float* ed     = (float*)alloc((size_t)Nn * Hh * 4);
    float* logits = (float*)alloc((size_t)Nn * OUTC * 4);
    int*   deg    = (int*)alloc((size_t)(Nn + 1) * 4);
    int*   rowp   = (int*)alloc((size_t)(Nn + 1) * 4);
    int*   wp     = (int*)alloc((size_t)Nn * 4);
    int*   elist  = (int*)alloc((size_t)ETOT * 4);
    float* BmatT  = (float*)alloc((size_t)Dd * Dd * 4);
    float* bqk    = (float*)alloc((size_t)Dd * 4);
    float* WoWv   = (float*)alloc((size_t)Dd * Dd * 4);
    float* Mc     = (float*)alloc((size_t)OUTC * Dd * 4);
    float* tmpv   = (float*)alloc((size_t)Dd * 4);
    float* cvec   = (float*)alloc((size_t)OUTC * 4);
    float* bsum   = (float*)alloc((size_t)OUTC * 4);
    float* bsq    = (float*)alloc((size_t)OUTC * 4);

    k_bmat<<<(Dd * Dd + Dd + 255) / 256, 256, 0, stream>>>(Wqkv, bqkv, BmatT, bqk);
    k_wowv<<<(Dd * Dd + Dd + 255) / 256, 256, 0, stream>>>(Wo, Wqkv, bqkv, bo, WoWv, tmpv);
    k_mcomb<<<(OUTC * Dd + OUTC + 255) / 256, 256, 0, stream>>>(Wout, WoWv, tmpv, bout, Mc, cvec);

    for (int t = 0; t < Tt; ++t) {
        const int* srcp = eidx + (size_t)t * 2 * Ee;
        const int* dstp = srcp + Ee;
        hipMemsetAsync(deg, 0, (size_t)(Nn + 1) * 4, stream);
        k_deg<<<(ETOT + 255) / 256, 256, 0, stream>>>(dstp, deg);
        k_scan<<<1, 256, 0, stream>>>(deg, rowp, wp);
        k_fill<<<(ETOT + 255) / 256, 256, 0, stream>>>(srcp, dstp, wp, elist);

        // layer 1: h = feats_t @ W1^T   (50000x128 @ 128x256)
        k_gemm_nt<128, 128, 16, 8, 8><<<dim3(Dd / 128, (Nn + 127) / 128), dim3(16, 16), 0, stream>>>(
            feats + (size_t)t * Nn * FIN, W1, nullptr, bufH, Nn, Dd, FIN);
        k_esed<<<(Nn * Hh + 255) / 256, 256, 0, stream>>>(bufH, a_s1, a_d1, es, ed);
        k_agg<false><<<Nn / 4, 256, 0, stream>>>(bufH, es, ed, rowp, elist, b1, nullptr, nullptr, bufX);

        // layer 2: h = x2 @ W2^T   (50000x256 @ 256x256)
        k_gemm_nt<128, 128, 16, 8, 8><<<dim3(Dd / 128, (Nn + 127) / 128), dim3(16, 16), 0, stream>>>(
            bufX, W2, nullptr, bufH, Nn, Dd, Dd);
        k_esed<<<(Nn * Hh + 255) / 256, 256, 0, stream>>>(bufH, a_s2, a_d2, es, ed);
        k_agg<true><<<Nn / 4, 256, 0, stream>>>(bufH, es, ed, rowp, elist, b2, ln_g, ln_b,
                                                emb + (size_t)t * Nn * Dd);
    }

    // qt = emb_last @ BmatT^T + bqk
    k_gemm_nt<128, 128, 16, 8, 8><<<dim3(Dd / 128, (Nn + 127) / 128), dim3(16, 16), 0, stream>>>(
        emb + (size_t)(Tt - 1) * Nn * Dd, BmatT, bqk, bufH, Nn, Dd, Dd);
    k_attn<<<Nn / 4, 256, 0, stream>>>(emb, bufH, bufX);
    // logits = z @ Mc^T + cvec   (50000x256 @ 256x64)
    k_gemm_nt<128, 64, 16, 8, 8><<<dim3(1, (Nn + 127) / 128), dim3(8, 16), 0, stream>>>(
        bufX, Mc, cvec, logits, Nn, OUTC, Dd);

    hipMemsetAsync(bsum, 0, OUTC * 4, stream);
    hipMemsetAsync(bsq, 0, OUTC * 4, stream);
    k_bnstat<<<256, 256, 0, stream>>>(logits, bsum, bsq);
    k_final<<<Nn / 4, 256, 0, stream>>>(logits, bsum, bsq, bn_g, bn_b, outp);
}

// Round 2
// 3139.534 us; speedup vs baseline: 1.5641x; 1.5641x over previous
//
#include <hip/hip_runtime.h>
#include <cstdint>
#include <cstddef>

#define Nn 50000
#define Ee 500000
#define ETOT (Ee + Nn)
#define Tt 8
#define FIN 128
#define Dd 256
#define Hh 32
#define Cc 8
#define OUTC 64
#define EPSC 1e-5f
#define G1 49   // ceil(50000/1024)

typedef __attribute__((ext_vector_type(8))) short bfrag;   // 8 bf16
typedef __attribute__((ext_vector_type(4))) float ffrag;   // 4 fp32 acc

static __device__ __forceinline__ unsigned short f2bf(float f) {
    unsigned u = __builtin_bit_cast(unsigned, f);
    u += 0x7fffu + ((u >> 16) & 1u);            // RNE
    return (unsigned short)(u >> 16);
}
static __device__ __forceinline__ float bf2f(unsigned short h) {
    unsigned u = ((unsigned)h) << 16;
    return __builtin_bit_cast(float, u);
}

// ---------------- fp32 -> bf16 cast (vectorized, grid-stride) ----------------
__global__ void k_cast(const float* __restrict__ s, unsigned short* __restrict__ d, long n4)
{
    long i = (long)blockIdx.x * 256 + threadIdx.x;
    long stride = (long)gridDim.x * 256;
    for (; i < n4; i += stride) {
        float4 v = ((const float4*)s)[i];
        ushort4 o;
        o.x = f2bf(v.x); o.y = f2bf(v.y); o.z = f2bf(v.z); o.w = f2bf(v.w);
        ((ushort4*)d)[i] = o;
    }
}

// ---------------- precompute: folded weight matrices (fp32) ----------------
__global__ void k_bmat(const float* __restrict__ Wqkv, const float* __restrict__ bqkv,
                       float* __restrict__ BmatT, float* __restrict__ bqk)
{
    int gid = blockIdx.x * 256 + threadIdx.x;
    if (gid < Dd * Dd) {
        int j = gid >> 8, k = gid & 255;
        float s = 0.f;
        for (int r = 0; r < Dd; ++r)
            s += Wqkv[r * Dd + k] * Wqkv[(Dd + r) * Dd + j];
        BmatT[j * Dd + k] = s;
    } else if (gid < Dd * Dd + Dd) {
        int j = gid - Dd * Dd;
        float s = 0.f;
        for (int r = 0; r < Dd; ++r)
            s += bqkv[r] * Wqkv[(Dd + r) * Dd + j];
        bqk[j] = s;
    }
}

__global__ void k_wowv(const float* __restrict__ Wo, const float* __restrict__ Wqkv,
                       const float* __restrict__ bqkv, const float* __restrict__ bo,
                       float* __restrict__ WoWv, float* __restrict__ tmpv)
{
    int gid = blockIdx.x * 256 + threadIdx.x;
    if (gid < Dd * Dd) {
        int i = gid >> 8, j = gid & 255;
        float s = 0.f;
        for (int r = 0; r < Dd; ++r)
            s += Wo[i * Dd + r] * Wqkv[(2 * Dd + r) * Dd + j];
        WoWv[i * Dd + j] = s;
    } else if (gid < Dd * Dd + Dd) {
        int i = gid - Dd * Dd;
        float s = 0.f;
        for (int r = 0; r < Dd; ++r)
            s += Wo[i * Dd + r] * bqkv[2 * Dd + r];
        tmpv[i] = s + bo[i];
    }
}

__global__ void k_mcomb(const float* __restrict__ Wout, const float* __restrict__ WoWv,
                        const float* __restrict__ tmpv, const float* __restrict__ bout,
                        float* __restrict__ Mc, float* __restrict__ cvec)
{
    int gid = blockIdx.x * 256 + threadIdx.x;
    if (gid < OUTC * Dd) {
        int o = gid >> 8, j = gid & 255;
        float s = 0.f;
        for (int i = 0; i < Dd; ++i)
            s += Wout[o * Dd + i] * WoWv[i * Dd + j];
        Mc[o * Dd + j] = s;
    } else if (gid < OUTC * Dd + OUTC) {
        int o = gid - OUTC * Dd;
        float s = 0.f;
        for (int i = 0; i < Dd; ++i)
            s += Wout[o * Dd + i] * tmpv[i];
        cvec[o] = s + bout[o];
    }
}

// ---------------- batched CSR build (all 8 timesteps) ----------------
__global__ void k_deg_all(const int* __restrict__ eidx, int* __restrict__ deg)
{
    int t = blockIdx.y;
    int e = blockIdx.x * 256 + threadIdx.x;
    if (e >= ETOT) return;
    const int* dstp = eidx + (size_t)t * 2 * Ee + Ee;
    int d = (e < Ee) ? dstp[e] : (e - Ee);
    atomicAdd(&deg[(size_t)t * Nn + d], 1);
}

__global__ void k_scan1(const int* __restrict__ deg, int* __restrict__ part)
{
    int t = blockIdx.y, b = blockIdx.x, tid = threadIdx.x;
    const int* dp = deg + (size_t)t * Nn;
    int base = b * 1024 + tid * 4;
    int s = 0;
    #pragma unroll
    for (int j = 0; j < 4; ++j) { int i = base + j; if (i < Nn) s += dp[i]; }
    __shared__ int red[256];
    red[tid] = s; __syncthreads();
    for (int off = 128; off > 0; off >>= 1) {
        if (tid < off) red[tid] += red[tid + off];
        __syncthreads();
    }
    if (tid == 0) part[t * G1 + b] = red[0];
}

__global__ void k_scan2(int* __restrict__ part, int* __restrict__ rowp)
{
    int t = blockIdx.x, lane = threadIdx.x;    // 64 threads
    int v = (lane < G1) ? part[t * G1 + lane] : 0;
    int s = v;
    #pragma unroll
    for (int off = 1; off < 64; off <<= 1) {
        int x = __shfl_up(s, off);
        if (lane >= off) s += x;
    }
    if (lane < G1) part[t * G1 + lane] = s - v;          // exclusive base per block
    if (lane == G1 - 1) rowp[(size_t)t * (Nn + 1) + Nn] = s;  // total
}

__global__ void k_scan3(const int* __restrict__ deg, const int* __restrict__ part,
                        int* __restrict__ rowp, int* __restrict__ wp)
{
    int t = blockIdx.y, b = blockIdx.x, tid = threadIdx.x;
    const int* dp = deg + (size_t)t * Nn;
    int base = b * 1024 + tid * 4;
    int v[4]; int s = 0;
    #pragma unroll
    for (int j = 0; j < 4; ++j) {
        v[j] = (base + j < Nn) ? dp[base + j] : 0;
        s += v[j];
    }
    __shared__ int sc[256];
    sc[tid] = s; __syncthreads();
    for (int off = 1; off < 256; off <<= 1) {
        int x = (tid >= off) ? sc[tid - off] : 0;
        __syncthreads();
        sc[tid] += x;
        __syncthreads();
    }
    int run = part[t * G1 + b] + (sc[tid] - s);
    int* rp = rowp + (size_t)t * (Nn + 1);
    int* wpp = wp + (size_t)t * Nn;
    #pragma unroll
    for (int j = 0; j < 4; ++j) {
        if (base + j < Nn) { rp[base + j] = run; wpp[base + j] = run; run += v[j]; }
    }
}

__global__ void k_fill_all(const int* __restrict__ eidx, int* __restrict__ wp,
                           int* __restrict__ elist)
{
    int t = blockIdx.y;
    int e = blockIdx.x * 256 + threadIdx.x;
    if (e >= ETOT) return;
    const int* srcp = eidx + (size_t)t * 2 * Ee;
    const int* dstp = srcp + Ee;
    int s, d;
    if (e < Ee) { s = srcp[e]; d = dstp[e]; }
    else        { s = e - Ee;  d = s; }
    int pos = atomicAdd(&wp[(size_t)t * Nn + d], 1);
    elist[(size_t)t * ETOT + pos] = s;
}

// ---------------- bf16 MFMA GEMM: C[M,N] = A[M,K] @ B[N,K]^T (+bias) ----------------
// One wave per 16-row tile, full N held in accumulators. Fragments loaded
// directly from global (weights are L1/L2-resident; A rows 16B-contiguous).
// A-frag: lane holds A[m0+(lane&15)][k0 + (lane>>4)*8 + j], j=0..7
// B-frag: lane holds B[n0+(lane&15)][k0 + (lane>>4)*8 + j]  (B = weight[N][K])
// C/D  : col = lane&15, row = (lane>>4)*4 + reg   [verified m89/m91]
template<int K, int N, bool OUT_BF16>
__global__ __launch_bounds__(256) void k_gemm(
    const unsigned short* __restrict__ A, const unsigned short* __restrict__ B,
    const float* __restrict__ bias, void* __restrict__ Cv, int M)
{
    constexpr int KSTEPS = K / 32, NSUB = N / 16;
    int wave = threadIdx.x >> 6, lane = threadIdx.x & 63;
    int rowTile = blockIdx.x * 4 + wave;
    if (rowTile * 16 >= M) return;
    int col = lane & 15, quad = lane >> 4;

    const unsigned short* arow = A + (size_t)(rowTile * 16 + col) * K + quad * 8;
    bfrag af[KSTEPS];
    #pragma unroll
    for (int ks = 0; ks < KSTEPS; ++ks)
        af[ks] = *(const bfrag*)(arow + ks * 32);

    ffrag acc[NSUB];
    #pragma unroll
    for (int ns = 0; ns < NSUB; ++ns) acc[ns] = ffrag{0.f, 0.f, 0.f, 0.f};

    #pragma unroll
    for (int ns = 0; ns < NSUB; ++ns) {
        const unsigned short* bp = B + (size_t)(ns * 16 + col) * K + quad * 8;
        #pragma unroll
        for (int ks = 0; ks < KSTEPS; ++ks) {
            bfrag bf = *(const bfrag*)(bp + ks * 32);
            acc[ns] = __builtin_amdgcn_mfma_f32_16x16x32_bf16(af[ks], bf, acc[ns], 0, 0, 0);
        }
    }

    int m0 = rowTile * 16;
    #pragma unroll
    for (int ns = 0; ns < NSUB; ++ns) {
        float bv = bias ? bias[ns * 16 + col] : 0.f;
        #pragma unroll
        for (int r = 0; r < 4; ++r) {
            int m = m0 + quad * 4 + r;
            float v = acc[ns][r] + bv;
            if (OUT_BF16)
                ((unsigned short*)Cv)[(size_t)m * N + ns * 16 + col] = f2bf(v);
            else
                ((float*)Cv)[(size_t)m * N + ns * 16 + col] = v;
        }
    }
}

// ---------------- attention logits per node: es/ed (bf16 h) ----------------
__global__ void k_esed(const unsigned short* __restrict__ h, const float* __restrict__ a_s,
                       const float* __restrict__ a_d, float* __restrict__ es, float* __restrict__ ed)
{
    int gid = blockIdx.x * 256 + threadIdx.x;
    if (gid >= Nn * Hh) return;
    int hh = gid & (Hh - 1);
    const unsigned short* hp = h + (size_t)(gid >> 5) * Dd + hh * Cc;
    bfrag hv = *(const bfrag*)hp;
    float se = 0.f, de = 0.f;
    #pragma unroll
    for (int i = 0; i < 8; ++i) {
        float x = bf2f((unsigned short)hv[i]);
        se += x * a_s[hh * Cc + i];
        de += x * a_d[hh * Cc + i];
    }
    es[gid] = se;
    ed[gid] = de;
}

// ---------------- GAT aggregation: one wave per dst node, online softmax ----------------
template<bool DO_LN>
__global__ __launch_bounds__(256) void k_agg(
    const unsigned short* __restrict__ h, const float* __restrict__ es, const float* __restrict__ ed,
    const int* __restrict__ rowp, const int* __restrict__ elist,
    const float* __restrict__ bvec, const float* __restrict__ lng, const float* __restrict__ lnb,
    unsigned short* __restrict__ outp)
{
    int lane = threadIdx.x & 63;
    int n = blockIdx.x * 4 + (threadIdx.x >> 6);
    if (n >= Nn) return;
    int hh = lane >> 1;          // head (8 channels = 2 lanes per head)
    int ch = lane * 4;           // 4 consecutive channels per lane
    float edv = ed[n * Hh + hh];
    int r0 = rowp[n], r1 = rowp[n + 1];
    float mX = -3.0e38f, den = 0.f;
    float ax = 0.f, ay = 0.f, az = 0.f, aw = 0.f;
    for (int i = r0; i < r1; ++i) {
        int s = elist[i];
        float x = es[s * Hh + hh] + edv;
        x = (x > 0.f) ? x : 0.2f * x;          // LeakyReLU(0.2)
        float mN = fmaxf(mX, x);
        float scl = __expf(mX - mN);
        float p = __expf(x - mN);
        den = den * scl + p;
        ushort4 hv = *(const ushort4*)(h + (size_t)s * Dd + ch);
        ax = ax * scl + p * bf2f(hv.x);
        ay = ay * scl + p * bf2f(hv.y);
        az = az * scl + p * bf2f(hv.z);
        aw = aw * scl + p * bf2f(hv.w);
        mX = mN;
    }
    float inv = 1.0f / den;
    float ox = ax * inv + bvec[ch];
    float oy = ay * inv + bvec[ch + 1];
    float oz = az * inv + bvec[ch + 2];
    float ow = aw * inv + bvec[ch + 3];
    if (DO_LN) {
        float s1 = ox + oy + oz + ow;
        float s2 = ox * ox + oy * oy + oz * oz + ow * ow;
        #pragma unroll
        for (int off = 32; off > 0; off >>= 1) {
            s1 += __shfl_xor(s1, off);
            s2 += __shfl_xor(s2, off);
        }
        float mu = s1 * (1.0f / Dd);
        float var = s2 * (1.0f / Dd) - mu * mu;
        float rstd = rsqrtf(var + EPSC);
        ox = fmaxf((ox - mu) * rstd * lng[ch]     + lnb[ch],     0.f);
        oy = fmaxf((oy - mu) * rstd * lng[ch + 1] + lnb[ch + 1], 0.f);
        oz = fmaxf((oz - mu) * rstd * lng[ch + 2] + lnb[ch + 2], 0.f);
        ow = fmaxf((ow - mu) * rstd * lng[ch + 3] + lnb[ch + 3], 0.f);
    }
    ushort4 o;
    o.x = f2bf(ox); o.y = f2bf(oy); o.z = f2bf(oz); o.w = f2bf(ow);
    *(ushort4*)(outp + (size_t)n * Dd + ch) = o;
}

// ---------------- temporal attention (last step only) ----------------
__global__ __launch_bounds__(256) void k_attn(const unsigned short* __restrict__ emb,
                                              const unsigned short* __restrict__ qt,
                                              unsigned short* __restrict__ z)
{
    int lane = threadIdx.x & 63;
    int n = blockIdx.x * 4 + (threadIdx.x >> 6);
    if (n >= Nn) return;
    ushort4 qv = *(const ushort4*)(qt + (size_t)n * Dd + lane * 4);
    float qx = bf2f(qv.x), qy = bf2f(qv.y), qz = bf2f(qv.z), qw = bf2f(qv.w);
    float ex[Tt], ey[Tt], ez[Tt], ew[Tt], sc[Tt];
    #pragma unroll
    for (int s = 0; s < Tt; ++s) {
        ushort4 ev = *(const ushort4*)(emb + ((size_t)s * Nn + n) * Dd + lane * 4);
        ex[s] = bf2f(ev.x); ey[s] = bf2f(ev.y); ez[s] = bf2f(ev.z); ew[s] = bf2f(ev.w);
        sc[s] = qx * ex[s] + qy * ey[s] + qz * ez[s] + qw * ew[s];
    }
    #pragma unroll
    for (int off = 32; off > 0; off >>= 1)
        #pragma unroll
        for (int s = 0; s < Tt; ++s) sc[s] += __shfl_xor(sc[s], off);
    float mx = -3.0e38f;
    #pragma unroll
    for (int s = 0; s < Tt; ++s) { sc[s] *= 0.0625f; mx = fmaxf(mx, sc[s]); }  // /sqrt(256)
    float w[Tt], den = 0.f;
    #pragma unroll
    for (int s = 0; s < Tt; ++s) { w[s] = __expf(sc[s] - mx); den += w[s]; }
    float inv = 1.0f / den;
    float zx = 0.f, zy = 0.f, zz = 0.f, zw = 0.f;
    #pragma unroll
    for (int s = 0; s < Tt; ++s) {
        float ws = w[s] * inv;
        zx += ws * ex[s]; zy += ws * ey[s]; zz += ws * ez[s]; zw += ws * ew[s];
    }
    ushort4 o;
    o.x = f2bf(zx); o.y = f2bf(zy); o.z = f2bf(zz); o.w = f2bf(zw);
    *(ushort4*)(z + (size_t)n * Dd + lane * 4) = o;
}

// ---------------- BatchNorm stats over N ----------------
__global__ __launch_bounds__(256) void k_bnstat(const float* __restrict__ logits,
                                                float* __restrict__ bsum, float* __restrict__ bsq)
{
    __shared__ float ls[256], lq[256];
    int t = threadIdx.x;
    int ch = t & 63;
    float s = 0.f, q = 0.f;
    for (int row = blockIdx.x * 4 + (t >> 6); row < Nn; row += gridDim.x * 4) {
        float v = logits[(size_t)row * OUTC + ch];
        s += v; q += v * v;
    }
    ls[t] = s; lq[t] = q;
    __syncthreads();
    if (t < 64) {
        s = ls[t] + ls[t + 64] + ls[t + 128] + ls[t + 192];
        q = lq[t] + lq[t + 64] + lq[t + 128] + lq[t + 192];
        atomicAdd(&bsum[t], s);
        atomicAdd(&bsq[t], q);
    }
}

// ---------------- BN apply + log_softmax ----------------
__global__ __launch_bounds__(256) void k_final(const float* __restrict__ logits,
                                               const float* __restrict__ bsum, const float* __restrict__ bsq,
                                               const float* __restrict__ g, const float* __restrict__ b,
                                               float* __restrict__ outp)
{
    int lane = threadIdx.x & 63;
    int row = blockIdx.x * 4 + (threadIdx.x >> 6);
    if (row >= Nn) return;
    float v = logits[(size_t)row * OUTC + lane];
    float mu = bsum[lane] * (1.0f / Nn);
    float var = bsq[lane] * (1.0f / Nn) - mu * mu;
    float y = (v - mu) * rsqrtf(var + EPSC) * g[lane] + b[lane];
    float mx = y;
    #pragma unroll
    for (int off = 32; off > 0; off >>= 1) mx = fmaxf(mx, __shfl_xor(mx, off));
    float ex = __expf(y - mx);
    float den = ex;
    #pragma unroll
    for (int off = 32; off > 0; off >>= 1) den += __shfl_xor(den, off);
    outp[(size_t)row * OUTC + lane] = y - mx - __logf(den);
}

// ---------------- launch ----------------
extern "C" void kernel_launch(void* const* d_in, const int* in_sizes, int n_in,
                              void* d_out, int out_size, void* d_ws, size_t ws_size,
                              hipStream_t stream)
{
    const float* feats = (const float*)d_in[0];
    const int*   eidx  = (const int*)d_in[1];
    const float* W1    = (const float*)d_in[2];
    const float* a_s1  = (const float*)d_in[3];
    const float* a_d1  = (const float*)d_in[4];
    const float* b1    = (const float*)d_in[5];
    const float* W2    = (const float*)d_in[6];
    const float* a_s2  = (const float*)d_in[7];
    const float* a_d2  = (const float*)d_in[8];
    const float* b2    = (const float*)d_in[9];
    const float* ln_g  = (const float*)d_in[10];
    const float* ln_b  = (const float*)d_in[11];
    const float* Wqkv  = (const float*)d_in[12];
    const float* bqkv  = (const float*)d_in[13];
    const float* Wo    = (const float*)d_in[14];
    const float* bo    = (const float*)d_in[15];
    const float* Wout  = (const float*)d_in[16];
    const float* bout  = (const float*)d_in[17];
    const float* bn_g  = (const float*)d_in[18];
    const float* bn_b  = (const float*)d_in[19];
    float* outp = (float*)d_out;

    char* p = (char*)d_ws;
    auto alloc = [&](size_t bytes) -> void* {
        void* r = (void*)p;
        p += (bytes + 255) & ~(size_t)255;
        return r;
    };
    unsigned short* featsb = (unsigned short*)alloc((size_t)Tt * Nn * FIN * 2);   // 102.4 MB
    unsigned short* embb   = (unsigned short*)alloc((size_t)Tt * Nn * Dd * 2);    // 204.8 MB
    unsigned short* hb     = (unsigned short*)alloc((size_t)Nn * Dd * 2);         // 25.6 MB
    unsigned short* xb     = (unsigned short*)alloc((size_t)Nn * Dd * 2);         // 25.6 MB
    float* es     = (float*)alloc((size_t)Nn * Hh * 4);
    float* ed     = (float*)alloc((size_t)Nn * Hh * 4);
    float* logits = (float*)alloc((size_t)Nn * OUTC * 4);
    int*   deg    = (int*)alloc((size_t)Tt * Nn * 4);
    int*   rowp   = (int*)alloc((size_t)Tt * (Nn + 1) * 4);
    int*   wp     = (int*)alloc((size_t)Tt * Nn * 4);
    int*   elist  = (int*)alloc((size_t)Tt * ETOT * 4);
    int*   part   = (int*)alloc((size_t)Tt * G1 * 4);
    float* BmatT  = (float*)alloc((size_t)Dd * Dd * 4);
    float* bqk    = (float*)alloc((size_t)Dd * 4);
    float* WoWv   = (float*)alloc((size_t)Dd * Dd * 4);
    float* Mc     = (float*)alloc((size_t)OUTC * Dd * 4);
    float* tmpv   = (float*)alloc((size_t)Dd * 4);
    float* cvec   = (float*)alloc((size_t)OUTC * 4);
    float* bsum   = (float*)alloc((size_t)OUTC * 4);
    float* bsq    = (float*)alloc((size_t)OUTC * 4);
    unsigned short* W1b    = (unsigned short*)alloc((size_t)Dd * FIN * 2);
    unsigned short* W2b    = (unsigned short*)alloc((size_t)Dd * Dd * 2);
    unsigned short* BmatTb = (unsigned short*)alloc((size_t)Dd * Dd * 2);
    unsigned short* Mcb    = (unsigned short*)alloc((size_t)OUTC * Dd * 2);

    // ---- precompute folded weights (fp32), then cast everything to bf16 ----
    k_bmat<<<(Dd * Dd + Dd + 255) / 256, 256, 0, stream>>>(Wqkv, bqkv, BmatT, bqk);
    k_wowv<<<(Dd * Dd + Dd + 255) / 256, 256, 0, stream>>>(Wo, Wqkv, bqkv, bo, WoWv, tmpv);
    k_mcomb<<<(OUTC * Dd + OUTC + 255) / 256, 256, 0, stream>>>(Wout, WoWv, tmpv, bout, Mc, cvec);

    k_cast<<<4096, 256, 0, stream>>>(feats, featsb, (long)Tt * Nn * FIN / 4);
    k_cast<<<(Dd * FIN / 4 + 255) / 256, 256, 0, stream>>>(W1, W1b, Dd * FIN / 4);
    k_cast<<<(Dd * Dd / 4 + 255) / 256, 256, 0, stream>>>(W2, W2b, Dd * Dd / 4);
    k_cast<<<(Dd * Dd / 4 + 255) / 256, 256, 0, stream>>>(BmatT, BmatTb, Dd * Dd / 4);
    k_cast<<<(OUTC * Dd / 4 + 255) / 256, 256, 0, stream>>>(Mc, Mcb, OUTC * Dd / 4);

    // ---- batched CSR build for all 8 timesteps ----
    hipMemsetAsync(deg, 0, (size_t)Tt * Nn * 4, stream);
    k_deg_all<<<dim3((ETOT + 255) / 256, Tt), 256, 0, stream>>>(eidx, deg);
    k_scan1<<<dim3(G1, Tt), 256, 0, stream>>>(deg, part);
    k_scan2<<<Tt, 64, 0, stream>>>(part, rowp);
    k_scan3<<<dim3(G1, Tt), 256, 0, stream>>>(deg, part, rowp, wp);
    k_fill_all<<<dim3((ETOT + 255) / 256, Tt), 256, 0, stream>>>(eidx, wp, elist);

    const int gemmGrid = (Nn / 16 + 3) / 4;   // 3125 row tiles, 4 waves/block
    for (int t = 0; t < Tt; ++t) {
        const int* rp = rowp + (size_t)t * (Nn + 1);
        const int* el = elist + (size_t)t * ETOT;
        // layer 1: h = feats_t @ W1^T
        k_gemm<FIN, Dd, true><<<gemmGrid, 256, 0, stream>>>(
            featsb + (size_t)t * Nn * FIN, W1b, nullptr, hb, Nn);
        k_esed<<<(Nn * Hh + 255) / 256, 256, 0, stream>>>(hb, a_s1, a_d1, es, ed);
        k_agg<false><<<Nn / 4, 256, 0, stream>>>(hb, es, ed, rp, el, b1, nullptr, nullptr, xb);
        // layer 2: h = x @ W2^T
        k_gemm<Dd, Dd, true><<<gemmGrid, 256, 0, stream>>>(xb, W2b, nullptr, hb, Nn);
        k_esed<<<(Nn * Hh + 255) / 256, 256, 0, stream>>>(hb, a_s2, a_d2, es, ed);
        k_agg<true><<<Nn / 4, 256, 0, stream>>>(hb, es, ed, rp, el, b2, ln_g, ln_b,
                                                embb + (size_t)t * Nn * Dd);
    }

    // qt = emb_last @ BmatT^T + bqk   (bf16 out, reuse hb)
    k_gemm<Dd, Dd, true><<<gemmGrid, 256, 0, stream>>>(
        embb + (size_t)(Tt - 1) * Nn * Dd, BmatTb, bqk, hb, Nn);
    k_attn<<<Nn / 4, 256, 0, stream>>>(embb, hb, xb);
    // logits = z @ Mc^T + cvec   (fp32 out)
    k_gemm<Dd, OUTC, false><<<gemmGrid, 256, 0, stream>>>(xb, Mcb, cvec, logits, Nn);

    hipMemsetAsync(bsum, 0, OUTC * 4, stream);
    hipMemsetAsync(bsq, 0, OUTC * 4, stream);
    k_bnstat<<<256, 256, 0, stream>>>(logits, bsum, bsq);
    k_final<<<Nn / 4, 256, 0, stream>>>(logits, bsum, bsq, bn_g, bn_b, outp);
}